// Round 5
// baseline (234.845 us; speedup 1.0000x reference)
//
#include <hip/hip_runtime.h>

#define NH   12
#define HD   64
#define H    768
#define B_   2
#define S_   2048
#define MTOT (B_*S_)   // 4096
#define KS   1536      // split storage width: [hi(768) | lo(768)]
#define KP   2304      // GEMM k' extent: hi*hi | hi*lo | lo*hi

typedef short bf16x8 __attribute__((ext_vector_type(8)));
typedef float f32x4  __attribute__((ext_vector_type(4)));
typedef float f32x16 __attribute__((ext_vector_type(16)));

#define MFMA16(a,b,c) __builtin_amdgcn_mfma_f32_16x16x32_bf16((a),(b),(c),0,0,0)
#define MFMA32(a,b,c) __builtin_amdgcn_mfma_f32_32x32x16_bf16((a),(b),(c),0,0,0)
#define GLL16(g,l) __builtin_amdgcn_global_load_lds( \
    (const __attribute__((address_space(1))) void*)(g), \
    (__attribute__((address_space(3))) void*)(l), 16, 0, 0)

__device__ __forceinline__ unsigned short f2bf(float x){
    union { float f; unsigned u; } c; c.f = x;
    unsigned r = (c.u + 0x7FFFu + ((c.u >> 16) & 1u)) >> 16;   // RNE
    return (unsigned short)r;
}
__device__ __forceinline__ float bf2f(unsigned short b){
    union { unsigned u; float f; } c; c.u = ((unsigned)b) << 16;
    return c.f;
}

// ---------------------------------------------------------------------------
// Split pre-passes: fp32 row [768] -> bf16 [hi(768) | lo(768)]
// ---------------------------------------------------------------------------
__global__ __launch_bounds__(256) void split_x(
    const float* __restrict__ src, unsigned short* __restrict__ dst)
{
    const int m = blockIdx.x;
    const float* s = src + (size_t)m * H;
    unsigned short* d = dst + (size_t)m * KS;
    for (int k = threadIdx.x; k < H; k += 256){
        float v = s[k];
        unsigned short hi = f2bf(v);
        d[k]     = hi;
        d[H + k] = f2bf(v - bf2f(hi));
    }
}

__global__ __launch_bounds__(256) void split_w(
    const float* __restrict__ wq, const float* __restrict__ wk,
    const float* __restrict__ wv, const float* __restrict__ wo,
    unsigned short* __restrict__ Wqkv, unsigned short* __restrict__ Wo_)
{
    const int n = blockIdx.x;      // 0..767
    const int w = blockIdx.y;      // 0..3
    const float* src = (w==0)?wq:(w==1)?wk:(w==2)?wv:wo;
    unsigned short* dst = (w<3) ? &Wqkv[(size_t)(w*768 + n)*KS] : &Wo_[(size_t)n*KS];
    const float* s = src + (size_t)n * H;
    for (int k = threadIdx.x; k < H; k += 256){
        float v = s[k];
        unsigned short hi = f2bf(v);
        dst[k]     = hi;
        dst[H + k] = f2bf(v - bf2f(hi));
    }
}

// ---------------------------------------------------------------------------
// Split-bf16 GEMM (r2 structure, proven). 128x128 tile, 4 waves, BK=32.
// ---------------------------------------------------------------------------
template<int MODE>
__global__ __launch_bounds__(256) void gemm_split(
    const unsigned short* __restrict__ A, const unsigned short* __restrict__ Bm,
    const float* __restrict__ b0, const float* __restrict__ b1,
    const float* __restrict__ b2,
    float* __restrict__ out,
    unsigned short* __restrict__ Qh, unsigned short* __restrict__ Ql,
    unsigned short* __restrict__ Kh, unsigned short* __restrict__ Kl,
    unsigned short* __restrict__ Vh, unsigned short* __restrict__ Vl)
{
    __shared__ unsigned short As[128*32];
    __shared__ unsigned short Bs[128*32];
    const int tid = threadIdx.x, lane = tid & 63, wave = tid >> 6;
    const int m0 = blockIdx.x*128, n0 = blockIdx.y*128;
    const int wr = wave >> 1, wc = wave & 1;
    const int frow = lane & 15, foct = lane >> 4;
    const int arow = lane >> 2;
    const int achk = ((lane & 3) ^ (arow & 3)) * 8;
    const int fswz = (foct ^ (frow & 3)) * 8;

    f32x4 acc[4][4] = {};

    for (int kp = 0; kp < KP; kp += 32){
        const int ka = (kp < 768)  ? kp : kp - 768;
        const int kb = (kp < 1536) ? kp : kp - 1536;
        __syncthreads();
        #pragma unroll
        for (int i = 0; i < 2; ++i){
            const int r0 = (wave*2 + i)*16;
            const int row = r0 + arow;
            GLL16(A  + (size_t)(m0+row)*KS + ka + achk, &As[r0*32]);
            GLL16(Bm + (size_t)(n0+row)*KS + kb + achk, &Bs[r0*32]);
        }
        __syncthreads();
        bf16x8 af[4], bfv[4];
        #pragma unroll
        for (int i = 0; i < 4; ++i)
            af[i]  = *(const bf16x8*)&As[(wr*64 + 16*i + frow)*32 + fswz];
        #pragma unroll
        for (int j = 0; j < 4; ++j)
            bfv[j] = *(const bf16x8*)&Bs[(wc*64 + 16*j + frow)*32 + fswz];
        #pragma unroll
        for (int i = 0; i < 4; ++i)
            #pragma unroll
            for (int j = 0; j < 4; ++j)
                acc[i][j] = MFMA16(af[i], bfv[j], acc[i][j]);
    }

    if (MODE == 0){
        #pragma unroll
        for (int i = 0; i < 4; ++i){
            const int m = m0 + wr*64 + 16*i + 4*foct;
            #pragma unroll
            for (int j = 0; j < 4; ++j){
                const int n = n0 + wc*64 + 16*j + frow;
                const float bb = b0[n];
                #pragma unroll
                for (int r = 0; r < 4; ++r)
                    out[(size_t)(m + r)*H + n] = acc[i][j][r] + bb;
            }
        }
    } else {
        const int sect = n0 / 768;
        const float* bias = (sect==0) ? b0 : (sect==1) ? b1 : b2;
        const float qs = (sect==0) ? 0.125f : 1.0f;
        unsigned short* Ph = (sect==0) ? Qh : Kh;
        unsigned short* Pl = (sect==0) ? Ql : Kl;
        #pragma unroll
        for (int i = 0; i < 4; ++i){
            const int m  = m0 + wr*64 + 16*i + 4*foct;
            const int bb = m >> 11, ss = m & (S_-1);
            #pragma unroll
            for (int j = 0; j < 4; ++j){
                const int nn = (n0 - sect*768) + wc*64 + 16*j + frow;
                const float bv_ = bias[nn];
                const int hh = nn >> 6, dd = nn & 63;
                unsigned short hi[4], lo[4];
                #pragma unroll
                for (int r = 0; r < 4; ++r){
                    float v = (acc[i][j][r] + bv_) * qs;
                    hi[r] = f2bf(v);
                    lo[r] = f2bf(v - bf2f(hi[r]));
                }
                if (sect < 2){                         // [b][h][s][d]
                    const size_t base = ((size_t)(bb*NH + hh)*S_)*HD + dd;
                    #pragma unroll
                    for (int r = 0; r < 4; ++r){
                        Ph[base + (size_t)(ss + r)*HD] = hi[r];
                        Pl[base + (size_t)(ss + r)*HD] = lo[r];
                    }
                } else {                               // V transposed [b][h][d][s]
                    const size_t a = ((size_t)(bb*NH + hh)*HD + dd)*S_ + ss;
                    ushort4 ph; ph.x=hi[0]; ph.y=hi[1]; ph.z=hi[2]; ph.w=hi[3];
                    ushort4 pl; pl.x=lo[0]; pl.y=lo[1]; pl.z=lo[2]; pl.w=lo[3];
                    *(ushort4*)&Vh[a] = ph;
                    *(ushort4*)&Vl[a] = pl;
                }
            }
        }
    }
}

// ---------------------------------------------------------------------------
// Flash attention, 32x32x16 MFMA, swapped operands, SPLIT-K=2 (flash-
// decoding): blockIdx.z = b + 2*half; each block does 16 of 32 key-tiles and
// writes unnormalized partial O (fp32) + (m,l). Grid 1536 -> 5 blocks/CU
// (LDS-capped) = 10 waves/CU vs r4's 6. Combine kernel merges halves.
// ---------------------------------------------------------------------------
__global__ __launch_bounds__(128) void attn_mfma(
    const unsigned short* __restrict__ Qh, const unsigned short* __restrict__ Ql,
    const unsigned short* __restrict__ Kh, const unsigned short* __restrict__ Kl,
    const unsigned short* __restrict__ Vh, const unsigned short* __restrict__ Vl,
    const int* __restrict__ mask, float* __restrict__ Op, float* __restrict__ mlb)
{
    __shared__ unsigned short Ksh[64*64], Ksl[64*64], Vsh[64*64], Vsl[64*64];

    const int tid = threadIdx.x, lane = tid & 63, wave = tid >> 6;  // 2 waves
    const int q0 = blockIdx.x*64, h = blockIdx.y;
    const int b = blockIdx.z & 1, half = blockIdx.z >> 1;
    const int l31 = lane & 31, hi = lane >> 5, l7 = lane & 7;
    const size_t base  = (size_t)(b*NH + h)*S_;   // K rows [s][d]
    const size_t vbase = (size_t)(b*NH + h)*HD;   // V rows [d][s]

    const int srow = lane >> 3;                   // 8 rows per GLL (128B rows)
    const int schk = ((lane & 7) ^ srow) * 8;     // pre-swizzled source chunk
    const int NT = S_/64;
    const int t0 = half*(NT/2);

    // ---- Q fragments (B-operand: col=lane&31=q, k=(lane>>5)*8+e) ----
    bf16x8 qfh[4], qfl[4];
    {
        const size_t qr = (base + q0 + wave*32 + l31)*HD;
        #pragma unroll
        for (int ds = 0; ds < 4; ++ds){
            qfh[ds] = *(const bf16x8*)&Qh[qr + ds*16 + hi*8];
            qfl[ds] = *(const bf16x8*)&Ql[qr + ds*16 + hi*8];
        }
    }

    float mrow = -1e30f, lrow = 0.f;
    f32x16 o0 = {}, o1 = {};

    for (int tt = 0; tt < NT/2; ++tt){
        const int t = t0 + tt;
        __syncthreads();   // all waves done reading previous tile
        if (wave == 0){    // wave 0 stages K (hi+lo)
            #pragma unroll
            for (int i = 0; i < 8; ++i){
                const int r0 = i*8, row = r0 + srow;
                const size_t off = (base + t*64 + row)*HD + schk;
                GLL16(Kh + off, &Ksh[r0*64]);
                GLL16(Kl + off, &Ksl[r0*64]);
            }
        } else {           // wave 1 stages V^T (hi+lo)
            #pragma unroll
            for (int i = 0; i < 8; ++i){
                const int r0 = i*8, row = r0 + srow;
                const size_t off = (vbase + row)*S_ + t*64 + schk;
                GLL16(Vh + off, &Vsh[r0*64]);
                GLL16(Vl + off, &Vsl[r0*64]);
            }
        }
        __syncthreads();   // implicit vmcnt(0) drain: tiles visible

        // ---- S^T = K (Q/8)^T : 3 split terms, 24 mfma ----
        f32x16 s0 = {}, s1 = {};
        __builtin_amdgcn_s_setprio(1);
        #pragma unroll
        for (int ds = 0; ds < 4; ++ds){
            const int c0 = ((2*ds + hi) ^ l7)*8;
            {
                const int ad = l31*64 + c0;
                const bf16x8 kh0 = *(const bf16x8*)&Ksh[ad];
                const bf16x8 kl0 = *(const bf16x8*)&Ksl[ad];
                s0 = MFMA32(kh0, qfh[ds], s0);
                s0 = MFMA32(kl0, qfh[ds], s0);
                s0 = MFMA32(kh0, qfl[ds], s0);
            }
            {
                const int ad = (32 + l31)*64 + c0;
                const bf16x8 kh1 = *(const bf16x8*)&Ksh[ad];
                const bf16x8 kl1 = *(const bf16x8*)&Ksl[ad];
                s1 = MFMA32(kh1, qfh[ds], s1);
                s1 = MFMA32(kh1, qfl[ds], s1);
                s1 = MFMA32(kl1, qfh[ds], s1);
            }
        }
        __builtin_amdgcn_s_setprio(0);

        // ---- mask (ballot -> 64-bit; all-ones path is a skipped branch) ----
        {
            const unsigned long long mb =
                __ballot(mask[(size_t)b*S_ + t*64 + lane] != 0);
            if (~mb){
                #pragma unroll
                for (int r = 0; r < 16; ++r){
                    const int key = (r&3) + 8*(r>>2) + 4*hi;
                    if (!((mb >> key) & 1))        s0[r] = -1e9f;
                    if (!((mb >> (key + 32)) & 1)) s1[r] = -1e9f;
                }
            }
        }

        // ---- online softmax: lane-local over 32 keys + 1 cross-half shfl ----
        float vmax = -1e30f;
        #pragma unroll
        for (int r = 0; r < 16; ++r) vmax = fmaxf(vmax, fmaxf(s0[r], s1[r]));
        vmax = fmaxf(vmax, __shfl_xor(vmax, 32));
        const float mnew = fmaxf(mrow, vmax);
        const float sc = __expf(mrow - mnew);
        mrow = mnew;
        float ps = 0.f;
        #pragma unroll
        for (int r = 0; r < 16; ++r){
            s0[r] = __expf(s0[r] - mnew);
            s1[r] = __expf(s1[r] - mnew);
            ps += s0[r] + s1[r];
        }
        ps += __shfl_xor(ps, 32);
        lrow = lrow*sc + ps;
        #pragma unroll
        for (int r = 0; r < 16; ++r){ o0[r] *= sc; o1[r] *= sc; }

        // ---- pack P^T to bf16 B-frags in-register (cvt_pk + swap) ----
        bf16x8 pf[4];
        #pragma unroll
        for (int s = 0; s < 4; ++s){
            const f32x16& pv = (s < 2) ? s0 : s1;
            const int rb = (s & 1)*8;
            unsigned w0, w1, w2, w3;
            asm("v_cvt_pk_bf16_f32 %0, %1, %2" : "=v"(w0) : "v"(pv[rb+0]), "v"(pv[rb+1]));
            asm("v_cvt_pk_bf16_f32 %0, %1, %2" : "=v"(w1) : "v"(pv[rb+2]), "v"(pv[rb+3]));
            asm("v_cvt_pk_bf16_f32 %0, %1, %2" : "=v"(w2) : "v"(pv[rb+4]), "v"(pv[rb+5]));
            asm("v_cvt_pk_bf16_f32 %0, %1, %2" : "=v"(w3) : "v"(pv[rb+6]), "v"(pv[rb+7]));
            const unsigned t0_ = (unsigned)__shfl_xor((int)w0, 32);
            const unsigned t1_ = (unsigned)__shfl_xor((int)w1, 32);
            const unsigned t2_ = (unsigned)__shfl_xor((int)w2, 32);
            const unsigned t3_ = (unsigned)__shfl_xor((int)w3, 32);
            union { uint4 u; bf16x8 v; } pk;
            pk.u.x = hi ? t2_ : w0;   // keys 8h+{0,1}
            pk.u.y = hi ? t3_ : w1;   // keys 8h+{2,3}
            pk.u.z = hi ? w2 : t0_;   // keys 8h+{4,5}
            pk.u.w = hi ? w3 : t1_;   // keys 8h+{6,7}
            pf[s] = pk.v;
        }

        // ---- O^T += V^T P^T : 16 mfma ----
        __builtin_amdgcn_s_setprio(1);
        #pragma unroll
        for (int s = 0; s < 4; ++s){
            const int c0 = ((2*s + hi) ^ l7)*8;
            const bf16x8 vh0 = *(const bf16x8*)&Vsh[l31*64 + c0];
            const bf16x8 vl0 = *(const bf16x8*)&Vsl[l31*64 + c0];
            o0 = MFMA32(vh0, pf[s], o0);
            o0 = MFMA32(vl0, pf[s], o0);
            const bf16x8 vh1 = *(const bf16x8*)&Vsh[(32 + l31)*64 + c0];
            const bf16x8 vl1 = *(const bf16x8*)&Vsl[(32 + l31)*64 + c0];
            o1 = MFMA32(vh1, pf[s], o1);
            o1 = MFMA32(vl1, pf[s], o1);
        }
        __builtin_amdgcn_s_setprio(0);
    }

    // ---- epilogue: store UNNORMALIZED partial O (fp32) + (m,l) ----
    // lane's q = q0+wave*32+l31; d(reg=a*4+j, dblk) = dblk*32 + 8a + 4hi + j
    const int qg = q0 + wave*32 + l31;
    float* Od = Op + ((((size_t)half*B_ + b)*NH + h)*S_ + qg)*HD;
    #pragma unroll
    for (int dblk = 0; dblk < 2; ++dblk){
        const f32x16& ov = dblk ? o1 : o0;
        #pragma unroll
        for (int a = 0; a < 4; ++a){
            const int d = dblk*32 + 8*a + 4*hi;
            f32x4 v; v[0]=ov[a*4+0]; v[1]=ov[a*4+1]; v[2]=ov[a*4+2]; v[3]=ov[a*4+3];
            *(f32x4*)&Od[d] = v;
        }
    }
    if (hi == 0){
        const size_t mi = (((size_t)half*B_ + b)*NH + h)*S_ + qg;
        mlb[mi*2]     = mrow;
        mlb[mi*2 + 1] = lrow;
    }
}

// ---------------------------------------------------------------------------
// Merge the two k-halves: O = (O0 w0 + O1 w1) / (l0 w0 + l1 w1), w_i=e^{m_i-m}
// Thread = (q, 4 d's); writes Cs in split-bf16 form for the out-proj GEMM.
// ---------------------------------------------------------------------------
__global__ __launch_bounds__(256) void attn_combine(
    const float* __restrict__ Op, const float* __restrict__ mlb,
    unsigned short* __restrict__ Cs)
{
    const int tid = threadIdx.x;
    const int gq = blockIdx.x*16 + (tid >> 4);       // over B*NH*S
    const int dl = (tid & 15)*4;
    const int s = gq & (S_-1);
    const int bh = gq >> 11;
    const int h = bh % NH, b = bh / NH;
    const size_t NQ = (size_t)B_*NH*S_;

    const float m0 = mlb[(size_t)gq*2],      l0 = mlb[(size_t)gq*2 + 1];
    const float m1 = mlb[(NQ + gq)*2],       l1 = mlb[(NQ + gq)*2 + 1];
    const float mm = fmaxf(m0, m1);
    const float w0 = __expf(m0 - mm), w1 = __expf(m1 - mm);
    const float inv = 1.0f / (l0*w0 + l1*w1);

    const float4 O0 = *(const float4*)&Op[(size_t)gq*HD + dl];
    const float4 O1 = *(const float4*)&Op[(NQ + gq)*HD + dl];
    float v0 = (O0.x*w0 + O1.x*w1)*inv;
    float v1 = (O0.y*w0 + O1.y*w1)*inv;
    float v2 = (O0.z*w0 + O1.z*w1)*inv;
    float v3 = (O0.w*w0 + O1.w*w1)*inv;

    const size_t g = ((size_t)b*S_ + s)*KS + h*HD + dl;
    ushort4 ph, pl;
    ph.x = f2bf(v0); pl.x = f2bf(v0 - bf2f(ph.x));
    ph.y = f2bf(v1); pl.y = f2bf(v1 - bf2f(ph.y));
    ph.z = f2bf(v2); pl.z = f2bf(v2 - bf2f(ph.z));
    ph.w = f2bf(v3); pl.w = f2bf(v3 - bf2f(ph.w));
    *(ushort4*)&Cs[g]       = ph;
    *(ushort4*)&Cs[g + 768] = pl;
}

extern "C" void kernel_launch(void* const* d_in, const int* in_sizes, int n_in,
                              void* d_out, int out_size, void* d_ws, size_t ws_size,
                              hipStream_t stream) {
    const float* hs = (const float*)d_in[0];
    const int*  msk = (const int*)  d_in[1];
    const float* wq = (const float*)d_in[2];
    const float* bq = (const float*)d_in[3];
    const float* wk = (const float*)d_in[4];
    const float* bk = (const float*)d_in[5];
    const float* wv = (const float*)d_in[6];
    const float* bv = (const float*)d_in[7];
    const float* wo = (const float*)d_in[8];
    const float* bo = (const float*)d_in[9];
    float* out = (float*)d_out;

    const size_t XS_E   = (size_t)MTOT*KS;
    const size_t WQKV_E = (size_t)2304*KS;
    const size_t WO_E   = (size_t)768*KS;
    const size_t QKV_E  = (size_t)B_*NH*S_*HD;   // 3,145,728

    unsigned short* p = (unsigned short*)d_ws;
    unsigned short* Xs   = p; p += XS_E;          // later reused as Cs
    unsigned short* Wqkv = p; p += WQKV_E;
    unsigned short* Wo_  = p; p += WO_E;
    unsigned short* Qh = p; p += QKV_E;
    unsigned short* Ql = p; p += QKV_E;
    unsigned short* Kh = p; p += QKV_E;
    unsigned short* Kl = p; p += QKV_E;
    unsigned short* Vh = p; p += QKV_E;
    unsigned short* Vl = p; p += QKV_E;
    float* Op  = (float*)p;                       // 2*QKV_E floats (25.2 MB)
    float* mlb = Op + 2*QKV_E;                    // 2*B*NH*S*2 floats (0.8 MB)
    unsigned short* Cs = Xs;

    split_x<<<dim3(MTOT), 256, 0, stream>>>(hs, Xs);
    split_w<<<dim3(768, 4), 256, 0, stream>>>(wq, wk, wv, wo, Wqkv, Wo_);
    gemm_split<1><<<dim3(MTOT/128, KP/128), 256, 0, stream>>>(
        Xs, Wqkv, bq, bk, bv, nullptr, Qh, Ql, Kh, Kl, Vh, Vl);
    attn_mfma<<<dim3(S_/64, NH, B_*2), 128, 0, stream>>>(
        Qh, Ql, Kh, Kl, Vh, Vl, msk, Op, mlb);
    attn_combine<<<dim3((B_*NH*S_)/16), 256, 0, stream>>>(Op, mlb, Cs);
    gemm_split<0><<<dim3(MTOT/128, H/128), 256, 0, stream>>>(
        Cs, Wo_, bo, nullptr, nullptr, out,
        nullptr, nullptr, nullptr, nullptr, nullptr, nullptr);
}

// Round 6
// 217.665 us; speedup vs baseline: 1.0789x; 1.0789x over previous
//
#include <hip/hip_runtime.h>

#define NH   12
#define HD   64
#define H    768
#define B_   2
#define S_   2048
#define MTOT (B_*S_)   // 4096
#define KS   1536      // split storage width: [hi(768) | lo(768)]
#define KP   2304      // GEMM k' extent: hi*hi | hi*lo | lo*hi

typedef short bf16x8 __attribute__((ext_vector_type(8)));
typedef float f32x4  __attribute__((ext_vector_type(4)));
typedef float f32x16 __attribute__((ext_vector_type(16)));

#define MFMA16(a,b,c) __builtin_amdgcn_mfma_f32_16x16x32_bf16((a),(b),(c),0,0,0)
#define MFMA32(a,b,c) __builtin_amdgcn_mfma_f32_32x32x16_bf16((a),(b),(c),0,0,0)
#define GLL16(g,l) __builtin_amdgcn_global_load_lds( \
    (const __attribute__((address_space(1))) void*)(g), \
    (__attribute__((address_space(3))) void*)(l), 16, 0, 0)

__device__ __forceinline__ unsigned short f2bf(float x){
    union { float f; unsigned u; } c; c.f = x;
    unsigned r = (c.u + 0x7FFFu + ((c.u >> 16) & 1u)) >> 16;   // RNE
    return (unsigned short)r;
}
__device__ __forceinline__ float bf2f(unsigned short b){
    union { unsigned u; float f; } c; c.u = ((unsigned)b) << 16;
    return c.f;
}

// ---------------------------------------------------------------------------
// Split pre-passes: fp32 row [768] -> bf16 [hi(768) | lo(768)]
// ---------------------------------------------------------------------------
__global__ __launch_bounds__(256) void split_x(
    const float* __restrict__ src, unsigned short* __restrict__ dst)
{
    const int m = blockIdx.x;
    const float* s = src + (size_t)m * H;
    unsigned short* d = dst + (size_t)m * KS;
    for (int k = threadIdx.x; k < H; k += 256){
        float v = s[k];
        unsigned short hi = f2bf(v);
        d[k]     = hi;
        d[H + k] = f2bf(v - bf2f(hi));
    }
}

__global__ __launch_bounds__(256) void split_w(
    const float* __restrict__ wq, const float* __restrict__ wk,
    const float* __restrict__ wv, const float* __restrict__ wo,
    unsigned short* __restrict__ Wqkv, unsigned short* __restrict__ Wo_)
{
    const int n = blockIdx.x;      // 0..767
    const int w = blockIdx.y;      // 0..3
    const float* src = (w==0)?wq:(w==1)?wk:(w==2)?wv:wo;
    unsigned short* dst = (w<3) ? &Wqkv[(size_t)(w*768 + n)*KS] : &Wo_[(size_t)n*KS];
    const float* s = src + (size_t)n * H;
    for (int k = threadIdx.x; k < H; k += 256){
        float v = s[k];
        unsigned short hi = f2bf(v);
        dst[k]     = hi;
        dst[H + k] = f2bf(v - bf2f(hi));
    }
}

// ---------------------------------------------------------------------------
// Split-bf16 GEMM (r2 structure, proven). 128x128 tile, 4 waves, BK=32.
// ---------------------------------------------------------------------------
template<int MODE>
__global__ __launch_bounds__(256) void gemm_split(
    const unsigned short* __restrict__ A, const unsigned short* __restrict__ Bm,
    const float* __restrict__ b0, const float* __restrict__ b1,
    const float* __restrict__ b2,
    float* __restrict__ out,
    unsigned short* __restrict__ Qh, unsigned short* __restrict__ Ql,
    unsigned short* __restrict__ Kh, unsigned short* __restrict__ Kl,
    unsigned short* __restrict__ Vh)
{
    __shared__ unsigned short As[128*32];
    __shared__ unsigned short Bs[128*32];
    const int tid = threadIdx.x, lane = tid & 63, wave = tid >> 6;
    const int m0 = blockIdx.x*128, n0 = blockIdx.y*128;
    const int wr = wave >> 1, wc = wave & 1;
    const int frow = lane & 15, foct = lane >> 4;
    const int arow = lane >> 2;
    const int achk = ((lane & 3) ^ (arow & 3)) * 8;
    const int fswz = (foct ^ (frow & 3)) * 8;

    f32x4 acc[4][4] = {};

    for (int kp = 0; kp < KP; kp += 32){
        const int ka = (kp < 768)  ? kp : kp - 768;
        const int kb = (kp < 1536) ? kp : kp - 1536;
        __syncthreads();
        #pragma unroll
        for (int i = 0; i < 2; ++i){
            const int r0 = (wave*2 + i)*16;
            const int row = r0 + arow;
            GLL16(A  + (size_t)(m0+row)*KS + ka + achk, &As[r0*32]);
            GLL16(Bm + (size_t)(n0+row)*KS + kb + achk, &Bs[r0*32]);
        }
        __syncthreads();
        bf16x8 af[4], bfv[4];
        #pragma unroll
        for (int i = 0; i < 4; ++i)
            af[i]  = *(const bf16x8*)&As[(wr*64 + 16*i + frow)*32 + fswz];
        #pragma unroll
        for (int j = 0; j < 4; ++j)
            bfv[j] = *(const bf16x8*)&Bs[(wc*64 + 16*j + frow)*32 + fswz];
        #pragma unroll
        for (int i = 0; i < 4; ++i)
            #pragma unroll
            for (int j = 0; j < 4; ++j)
                acc[i][j] = MFMA16(af[i], bfv[j], acc[i][j]);
    }

    if (MODE == 0){
        #pragma unroll
        for (int i = 0; i < 4; ++i){
            const int m = m0 + wr*64 + 16*i + 4*foct;
            #pragma unroll
            for (int j = 0; j < 4; ++j){
                const int n = n0 + wc*64 + 16*j + frow;
                const float bb = b0[n];
                #pragma unroll
                for (int r = 0; r < 4; ++r)
                    out[(size_t)(m + r)*H + n] = acc[i][j][r] + bb;
            }
        }
    } else {
        const int sect = n0 / 768;
        const float* bias = (sect==0) ? b0 : (sect==1) ? b1 : b2;
        const float qs = (sect==0) ? 0.125f : 1.0f;
        unsigned short* Ph = (sect==0) ? Qh : Kh;
        unsigned short* Pl = (sect==0) ? Ql : Kl;
        #pragma unroll
        for (int i = 0; i < 4; ++i){
            const int m  = m0 + wr*64 + 16*i + 4*foct;
            const int bb = m >> 11, ss = m & (S_-1);
            #pragma unroll
            for (int j = 0; j < 4; ++j){
                const int nn = (n0 - sect*768) + wc*64 + 16*j + frow;
                const float bv_ = bias[nn];
                const int hh = nn >> 6, dd = nn & 63;
                unsigned short hi[4], lo[4];
                #pragma unroll
                for (int r = 0; r < 4; ++r){
                    float v = (acc[i][j][r] + bv_) * qs;
                    hi[r] = f2bf(v);
                    lo[r] = f2bf(v - bf2f(hi[r]));
                }
                if (sect < 2){                         // [b][h][s][d]
                    const size_t base = ((size_t)(bb*NH + hh)*S_)*HD + dd;
                    #pragma unroll
                    for (int r = 0; r < 4; ++r){
                        Ph[base + (size_t)(ss + r)*HD] = hi[r];
                        Pl[base + (size_t)(ss + r)*HD] = lo[r];
                    }
                } else {                               // V^T [b][h][d][s], hi only
                    const size_t a = ((size_t)(bb*NH + hh)*HD + dd)*S_ + ss;
                    ushort4 ph; ph.x=hi[0]; ph.y=hi[1]; ph.z=hi[2]; ph.w=hi[3];
                    *(ushort4*)&Vh[a] = ph;
                }
            }
        }
    }
}

// ---------------------------------------------------------------------------
// Flash attention, 32x32x16 MFMA, swapped operands. 2 waves x 64 q-rows each
// (two 32-col B-frags share every K/V LDS read -> 2x intensity, 4 indep acc
// chains). Split-K=2 (flash-decoding). Double-buffered LDS (48KB) with
// counted s_waitcnt vmcnt(12) + raw s_barrier (NO full drains): stage t+2
// issued after compute of t, so staging latency is fully hidden.
// Mask preloaded to a per-lane 32-bit mask (no loads in the loop -> counted
// vmcnt stays exact). QK^T = 3 split terms; PV = hi-term only (err ~2e-4).
// ---------------------------------------------------------------------------
__global__ __launch_bounds__(128, 2) void attn_mfma(
    const unsigned short* __restrict__ Qh, const unsigned short* __restrict__ Ql,
    const unsigned short* __restrict__ Kh, const unsigned short* __restrict__ Kl,
    const unsigned short* __restrict__ Vh,
    const int* __restrict__ mask, float* __restrict__ Op, float* __restrict__ mlb)
{
    __shared__ unsigned short Ksh[2][64*64];
    __shared__ unsigned short Ksl[2][64*64];
    __shared__ unsigned short Vsh[2][64*64];

    const int tid = threadIdx.x, lane = tid & 63, wave = tid >> 6;  // 2 waves
    const int q0 = blockIdx.x*128, h = blockIdx.y;
    const int b = blockIdx.z & 1, half = blockIdx.z >> 1;
    const int l31 = lane & 31, hi = lane >> 5, l7 = lane & 7;
    const size_t base  = (size_t)(b*NH + h)*S_;   // K rows [s][d]
    const size_t vbase = (size_t)(b*NH + h)*HD;   // V rows [d][s]
    const int srow = lane >> 3;                   // 8 rows per GLL (128B rows)
    const int schk = ((lane & 7) ^ srow) * 8;     // pre-swizzled source chunk
    const int NTH = (S_/64)/2;                    // 16 tiles per half
    const int t0 = half*NTH;

    // each wave stages 12 GLL/tile: w0 = Kh(8)+Kl(0..31); w1 = Vh(8)+Kl(32..63)
    auto STAGE = [&](int bufi, int t){
        if (wave == 0){
            #pragma unroll
            for (int i = 0; i < 8; ++i){
                const int r0 = i*8, row = r0 + srow;
                GLL16(Kh + (base + (size_t)t*64 + row)*HD + schk, &Ksh[bufi][r0*64]);
            }
            #pragma unroll
            for (int i = 0; i < 4; ++i){
                const int r0 = i*8, row = r0 + srow;
                GLL16(Kl + (base + (size_t)t*64 + row)*HD + schk, &Ksl[bufi][r0*64]);
            }
        } else {
            #pragma unroll
            for (int i = 0; i < 8; ++i){
                const int r0 = i*8, row = r0 + srow;
                GLL16(Vh + (vbase + row)*S_ + (size_t)t*64 + schk, &Vsh[bufi][r0*64]);
            }
            #pragma unroll
            for (int i = 4; i < 8; ++i){
                const int r0 = i*8, row = r0 + srow;
                GLL16(Kl + (base + (size_t)t*64 + row)*HD + schk, &Ksl[bufi][r0*64]);
            }
        }
    };

    // ---- mask bits: lane L holds keys L*32..L*32+31 (batch b) ----
    unsigned mbits = 0;
    {
        const int* mp = mask + (size_t)b*S_ + lane*32;
        #pragma unroll
        for (int j = 0; j < 32; ++j) mbits |= (mp[j] ? 1u : 0u) << j;
    }

    // ---- Q fragments, two 32-col blocks (B-op: col=l31, k=hi*8+e) ----
    bf16x8 qfhA[4], qflA[4], qfhB[4], qflB[4];
    {
        const size_t qrA = (base + q0 + wave*64      + l31)*HD;
        const size_t qrB = (base + q0 + wave*64 + 32 + l31)*HD;
        #pragma unroll
        for (int ds = 0; ds < 4; ++ds){
            qfhA[ds] = *(const bf16x8*)&Qh[qrA + ds*16 + hi*8];
            qflA[ds] = *(const bf16x8*)&Ql[qrA + ds*16 + hi*8];
            qfhB[ds] = *(const bf16x8*)&Qh[qrB + ds*16 + hi*8];
            qflB[ds] = *(const bf16x8*)&Ql[qrB + ds*16 + hi*8];
        }
    }

    STAGE(0, t0);
    STAGE(1, t0 + 1);

    float mA = -1e30f, lA = 0.f, mB = -1e30f, lB = 0.f;
    f32x16 oA0 = {}, oA1 = {}, oB0 = {}, oB1 = {};

    for (int tt = 0; tt < NTH; ++tt){
        const int t = t0 + tt, cur = tt & 1;
        if (tt + 1 < NTH) asm volatile("s_waitcnt vmcnt(12)" ::: "memory");
        else              asm volatile("s_waitcnt vmcnt(0)"  ::: "memory");
        asm volatile("s_barrier" ::: "memory");   // tile t visible to both waves

        // ---- S^T = K (Q/8)^T : 3 split terms x 2 q-blocks, 48 mfma ----
        f32x16 sA0 = {}, sA1 = {}, sB0 = {}, sB1 = {};
        __builtin_amdgcn_s_setprio(1);
        #pragma unroll
        for (int ds = 0; ds < 4; ++ds){
            const int c0 = ((2*ds + hi) ^ l7)*8;
            const bf16x8 kh0 = *(const bf16x8*)&Ksh[cur][l31*64 + c0];
            const bf16x8 kl0 = *(const bf16x8*)&Ksl[cur][l31*64 + c0];
            const bf16x8 kh1 = *(const bf16x8*)&Ksh[cur][(32+l31)*64 + c0];
            const bf16x8 kl1 = *(const bf16x8*)&Ksl[cur][(32+l31)*64 + c0];
            sA0 = MFMA32(kh0, qfhA[ds], sA0);
            sB0 = MFMA32(kh0, qfhB[ds], sB0);
            sA1 = MFMA32(kh1, qfhA[ds], sA1);
            sB1 = MFMA32(kh1, qfhB[ds], sB1);
            sA0 = MFMA32(kl0, qfhA[ds], sA0);
            sB0 = MFMA32(kl0, qfhB[ds], sB0);
            sA1 = MFMA32(kl1, qfhA[ds], sA1);
            sB1 = MFMA32(kl1, qfhB[ds], sB1);
            sA0 = MFMA32(kh0, qflA[ds], sA0);
            sB0 = MFMA32(kh0, qflB[ds], sB0);
            sA1 = MFMA32(kh1, qflA[ds], sA1);
            sB1 = MFMA32(kh1, qflB[ds], sB1);
        }
        __builtin_amdgcn_s_setprio(0);

        // ---- mask via preloaded bits (no memory ops) ----
        {
            const unsigned bm_lo = (unsigned)__shfl((int)mbits, 2*t);
            const unsigned bm_hi = (unsigned)__shfl((int)mbits, 2*t + 1);
            const unsigned long long mb = ((unsigned long long)bm_hi << 32) | bm_lo;
            if (~mb){
                #pragma unroll
                for (int r = 0; r < 16; ++r){
                    const int key = (r&3) + 8*(r>>2) + 4*hi;
                    if (!((mb >> key) & 1)){ sA0[r] = -1e9f; sB0[r] = -1e9f; }
                    if (!((mb >> (key+32)) & 1)){ sA1[r] = -1e9f; sB1[r] = -1e9f; }
                }
            }
        }

        // ================= q-block A: softmax + pack + PV =================
        {
            float vmax = -1e30f;
            #pragma unroll
            for (int r = 0; r < 16; ++r) vmax = fmaxf(vmax, fmaxf(sA0[r], sA1[r]));
            vmax = fmaxf(vmax, __shfl_xor(vmax, 32));
            if (!__all(vmax <= mA + 8.f)){          // T13 defer-rescale
                const float mnew = fmaxf(mA, vmax);
                const float sc = __expf(mA - mnew);
                mA = mnew; lA *= sc;
                #pragma unroll
                for (int r = 0; r < 16; ++r){ oA0[r] *= sc; oA1[r] *= sc; }
            }
            float ps = 0.f;
            #pragma unroll
            for (int r = 0; r < 16; ++r){
                sA0[r] = __expf(sA0[r] - mA);
                sA1[r] = __expf(sA1[r] - mA);
                ps += sA0[r] + sA1[r];
            }
            ps += __shfl_xor(ps, 32);
            lA += ps;

            bf16x8 pf[4];
            #pragma unroll
            for (int s = 0; s < 4; ++s){
                const f32x16& pv = (s < 2) ? sA0 : sA1;
                const int rb = (s & 1)*8;
                unsigned w0, w1, w2, w3;
                asm("v_cvt_pk_bf16_f32 %0, %1, %2" : "=v"(w0) : "v"(pv[rb+0]), "v"(pv[rb+1]));
                asm("v_cvt_pk_bf16_f32 %0, %1, %2" : "=v"(w1) : "v"(pv[rb+2]), "v"(pv[rb+3]));
                asm("v_cvt_pk_bf16_f32 %0, %1, %2" : "=v"(w2) : "v"(pv[rb+4]), "v"(pv[rb+5]));
                asm("v_cvt_pk_bf16_f32 %0, %1, %2" : "=v"(w3) : "v"(pv[rb+6]), "v"(pv[rb+7]));
                const unsigned u0 = (unsigned)__shfl_xor((int)w0, 32);
                const unsigned u1 = (unsigned)__shfl_xor((int)w1, 32);
                const unsigned u2 = (unsigned)__shfl_xor((int)w2, 32);
                const unsigned u3 = (unsigned)__shfl_xor((int)w3, 32);
                union { uint4 u; bf16x8 v; } pk;
                pk.u.x = hi ? u2 : w0;
                pk.u.y = hi ? u3 : w1;
                pk.u.z = hi ? w2 : u0;
                pk.u.w = hi ? w3 : u1;
                pf[s] = pk.v;
            }

            __builtin_amdgcn_s_setprio(1);
            #pragma unroll
            for (int s = 0; s < 4; ++s){
                const int c0 = ((2*s + hi) ^ l7)*8;
                const bf16x8 vh0 = *(const bf16x8*)&Vsh[cur][l31*64 + c0];
                const bf16x8 vh1 = *(const bf16x8*)&Vsh[cur][(32+l31)*64 + c0];
                oA0 = MFMA32(vh0, pf[s], oA0);
                oA1 = MFMA32(vh1, pf[s], oA1);
            }
            __builtin_amdgcn_s_setprio(0);
        }

        // ================= q-block B: softmax + pack + PV =================
        {
            float vmax = -1e30f;
            #pragma unroll
            for (int r = 0; r < 16; ++r) vmax = fmaxf(vmax, fmaxf(sB0[r], sB1[r]));
            vmax = fmaxf(vmax, __shfl_xor(vmax, 32));
            if (!__all(vmax <= mB + 8.f)){
                const float mnew = fmaxf(mB, vmax);
                const float sc = __expf(mB - mnew);
                mB = mnew; lB *= sc;
                #pragma unroll
                for (int r = 0; r < 16; ++r){ oB0[r] *= sc; oB1[r] *= sc; }
            }
            float ps = 0.f;
            #pragma unroll
            for (int r = 0; r < 16; ++r){
                sB0[r] = __expf(sB0[r] - mB);
                sB1[r] = __expf(sB1[r] - mB);
                ps += sB0[r] + sB1[r];
            }
            ps += __shfl_xor(ps, 32);
            lB += ps;

            bf16x8 pf[4];
            #pragma unroll
            for (int s = 0; s < 4; ++s){
                const f32x16& pv = (s < 2) ? sB0 : sB1;
                const int rb = (s & 1)*8;
                unsigned w0, w1, w2, w3;
                asm("v_cvt_pk_bf16_f32 %0, %1, %2" : "=v"(w0) : "v"(pv[rb+0]), "v"(pv[rb+1]));
                asm("v_cvt_pk_bf16_f32 %0, %1, %2" : "=v"(w1) : "v"(pv[rb+2]), "v"(pv[rb+3]));
                asm("v_cvt_pk_bf16_f32 %0, %1, %2" : "=v"(w2) : "v"(pv[rb+4]), "v"(pv[rb+5]));
                asm("v_cvt_pk_bf16_f32 %0, %1, %2" : "=v"(w3) : "v"(pv[rb+6]), "v"(pv[rb+7]));
                const unsigned u0 = (unsigned)__shfl_xor((int)w0, 32);
                const unsigned u1 = (unsigned)__shfl_xor((int)w1, 32);
                const unsigned u2 = (unsigned)__shfl_xor((int)w2, 32);
                const unsigned u3 = (unsigned)__shfl_xor((int)w3, 32);
                union { uint4 u; bf16x8 v; } pk;
                pk.u.x = hi ? u2 : w0;
                pk.u.y = hi ? u3 : w1;
                pk.u.z = hi ? w2 : u0;
                pk.u.w = hi ? w3 : u1;
                pf[s] = pk.v;
            }

            __builtin_amdgcn_s_setprio(1);
            #pragma unroll
            for (int s = 0; s < 4; ++s){
                const int c0 = ((2*s + hi) ^ l7)*8;
                const bf16x8 vh0 = *(const bf16x8*)&Vsh[cur][l31*64 + c0];
                const bf16x8 vh1 = *(const bf16x8*)&Vsh[cur][(32+l31)*64 + c0];
                oB0 = MFMA32(vh0, pf[s], oB0);
                oB1 = MFMA32(vh1, pf[s], oB1);
            }
            __builtin_amdgcn_s_setprio(0);
        }

        asm volatile("s_barrier" ::: "memory");   // both waves done with buf[cur]
        if (tt + 2 < NTH) STAGE(cur, t + 2);      // overwrite freed buffer
    }

    // ---- epilogue: store UNNORMALIZED partial O (fp32) + (m,l) ----
    #pragma unroll
    for (int qb = 0; qb < 2; ++qb){
        const int qg = q0 + wave*64 + qb*32 + l31;
        const f32x16& ov0 = qb ? oB0 : oA0;
        const f32x16& ov1 = qb ? oB1 : oA1;
        float* Od = Op + ((((size_t)half*B_ + b)*NH + h)*S_ + qg)*HD;
        #pragma unroll
        for (int a = 0; a < 4; ++a){
            const int d0 = 8*a + 4*hi;
            f32x4 v0, v1;
            #pragma unroll
            for (int r = 0; r < 4; ++r){ v0[r] = ov0[a*4+r]; v1[r] = ov1[a*4+r]; }
            *(f32x4*)&Od[d0]      = v0;
            *(f32x4*)&Od[32 + d0] = v1;
        }
        if (hi == 0){
            const size_t mi = (((size_t)half*B_ + b)*NH + h)*S_ + qg;
            mlb[mi*2]     = qb ? mB : mA;
            mlb[mi*2 + 1] = qb ? lB : lA;
        }
    }
}

// ---------------------------------------------------------------------------
// Merge the two k-halves: O = (O0 w0 + O1 w1) / (l0 w0 + l1 w1), w_i=e^{m_i-m}
// ---------------------------------------------------------------------------
__global__ __launch_bounds__(256) void attn_combine(
    const float* __restrict__ Op, const float* __restrict__ mlb,
    unsigned short* __restrict__ Cs)
{
    const int tid = threadIdx.x;
    const int gq = blockIdx.x*16 + (tid >> 4);       // over B*NH*S
    const int dl = (tid & 15)*4;
    const int s = gq & (S_-1);
    const int bh = gq >> 11;
    const int h = bh % NH, b = bh / NH;
    const size_t NQ = (size_t)B_*NH*S_;

    const float m0 = mlb[(size_t)gq*2],      l0 = mlb[(size_t)gq*2 + 1];
    const float m1 = mlb[(NQ + gq)*2],       l1 = mlb[(NQ + gq)*2 + 1];
    const float mm = fmaxf(m0, m1);
    const float w0 = __expf(m0 - mm), w1 = __expf(m1 - mm);
    const float inv = 1.0f / (l0*w0 + l1*w1);

    const float4 O0 = *(const float4*)&Op[(size_t)gq*HD + dl];
    const float4 O1 = *(const float4*)&Op[(NQ + gq)*HD + dl];
    float v0 = (O0.x*w0 + O1.x*w1)*inv;
    float v1 = (O0.y*w0 + O1.y*w1)*inv;
    float v2 = (O0.z*w0 + O1.z*w1)*inv;
    float v3 = (O0.w*w0 + O1.w*w1)*inv;

    const size_t g = ((size_t)b*S_ + s)*KS + h*HD + dl;
    ushort4 ph, pl;
    ph.x = f2bf(v0); pl.x = f2bf(v0 - bf2f(ph.x));
    ph.y = f2bf(v1); pl.y = f2bf(v1 - bf2f(ph.y));
    ph.z = f2bf(v2); pl.z = f2bf(v2 - bf2f(ph.z));
    ph.w = f2bf(v3); pl.w = f2bf(v3 - bf2f(ph.w));
    *(ushort4*)&Cs[g]       = ph;
    *(ushort4*)&Cs[g + 768] = pl;
}

extern "C" void kernel_launch(void* const* d_in, const int* in_sizes, int n_in,
                              void* d_out, int out_size, void* d_ws, size_t ws_size,
                              hipStream_t stream) {
    const float* hs = (const float*)d_in[0];
    const int*  msk = (const int*)  d_in[1];
    const float* wq = (const float*)d_in[2];
    const float* bq = (const float*)d_in[3];
    const float* wk = (const float*)d_in[4];
    const float* bk = (const float*)d_in[5];
    const float* wv = (const float*)d_in[6];
    const float* bv = (const float*)d_in[7];
    const float* wo = (const float*)d_in[8];
    const float* bo = (const float*)d_in[9];
    float* out = (float*)d_out;

    const size_t XS_E   = (size_t)MTOT*KS;
    const size_t WQKV_E = (size_t)2304*KS;
    const size_t WO_E   = (size_t)768*KS;
    const size_t QKV_E  = (size_t)B_*NH*S_*HD;   // 3,145,728

    unsigned short* p = (unsigned short*)d_ws;
    unsigned short* Xs   = p; p += XS_E;          // later reused as Cs
    unsigned short* Wqkv = p; p += WQKV_E;
    unsigned short* Wo_  = p; p += WO_E;
    unsigned short* Qh = p; p += QKV_E;
    unsigned short* Ql = p; p += QKV_E;
    unsigned short* Kh = p; p += QKV_E;
    unsigned short* Kl = p; p += QKV_E;
    unsigned short* Vh = p; p += QKV_E;
    float* Op  = (float*)p;                       // 2*QKV_E floats (25.2 MB)
    float* mlb = Op + 2*QKV_E;                    // 2*B*NH*S*2 floats (0.8 MB)
    unsigned short* Cs = Xs;

    split_x<<<dim3(MTOT), 256, 0, stream>>>(hs, Xs);
    split_w<<<dim3(768, 4), 256, 0, stream>>>(wq, wk, wv, wo, Wqkv, Wo_);
    gemm_split<1><<<dim3(MTOT/128, KP/128), 256, 0, stream>>>(
        Xs, Wqkv, bq, bk, bv, nullptr, Qh, Ql, Kh, Kl, Vh);
    attn_mfma<<<dim3(S_/128, NH, B_*2), 128, 0, stream>>>(
        Qh, Ql, Kh, Kl, Vh, msk, Op, mlb);
    attn_combine<<<dim3((B_*NH*S_)/16), 256, 0, stream>>>(Op, mlb, Cs);
    gemm_split<0><<<dim3(MTOT/128, H/128), 256, 0, stream>>>(
        Cs, Wo_, bo, nullptr, nullptr, out,
        nullptr, nullptr, nullptr, nullptr, nullptr);
}

// Round 7
// 152.835 us; speedup vs baseline: 1.5366x; 1.4242x over previous
//
#include <hip/hip_runtime.h>

#define NH   12
#define HD   64
#define H    768
#define B_   2
#define S_   2048
#define MTOT (B_*S_)   // 4096
#define KS   1536      // split storage width for ctx/Wo: [hi(768) | lo(768)]
#define KP   2304      // out-proj k' extent: hi*hi | hi*lo | lo*hi

typedef short bf16x8 __attribute__((ext_vector_type(8)));
typedef float f32x4  __attribute__((ext_vector_type(4)));
typedef float f32x16 __attribute__((ext_vector_type(16)));

#define MFMA16(a,b,c) __builtin_amdgcn_mfma_f32_16x16x32_bf16((a),(b),(c),0,0,0)
#define MFMA32(a,b,c) __builtin_amdgcn_mfma_f32_32x32x16_bf16((a),(b),(c),0,0,0)
#define GLL16(g,l) __builtin_amdgcn_global_load_lds( \
    (const __attribute__((address_space(1))) void*)(g), \
    (__attribute__((address_space(3))) void*)(l), 16, 0, 0)

__device__ __forceinline__ unsigned short f2bf(float x){
    union { float f; unsigned u; } c; c.f = x;
    unsigned r = (c.u + 0x7FFFu + ((c.u >> 16) & 1u)) >> 16;   // RNE
    return (unsigned short)r;
}
__device__ __forceinline__ float bf2f(unsigned short b){
    union { unsigned u; float f; } c; c.u = ((unsigned)b) << 16;
    return c.f;
}

// ---------------------------------------------------------------------------
// Pre-passes. X: hi-only cast (feeds 1-term QKV GEMM).
// W: Wq/Wk/Wv hi-only; Wo split [hi|lo] (out-proj stays 3-term).
// ---------------------------------------------------------------------------
__global__ __launch_bounds__(256) void cast_x(
    const float* __restrict__ src, unsigned short* __restrict__ dst)
{
    const int m = blockIdx.x;
    const float* s = src + (size_t)m * H;
    unsigned short* d = dst + (size_t)m * H;
    for (int k = threadIdx.x; k < H; k += 256) d[k] = f2bf(s[k]);
}

__global__ __launch_bounds__(256) void split_w(
    const float* __restrict__ wq, const float* __restrict__ wk,
    const float* __restrict__ wv, const float* __restrict__ wo,
    unsigned short* __restrict__ Wqkv, unsigned short* __restrict__ Wo_)
{
    const int n = blockIdx.x;      // 0..767
    const int w = blockIdx.y;      // 0..3
    const float* src = (w==0)?wq:(w==1)?wk:(w==2)?wv:wo;
    const float* s = src + (size_t)n * H;
    if (w < 3){
        unsigned short* dst = &Wqkv[(size_t)(w*768 + n)*H];
        for (int k = threadIdx.x; k < H; k += 256) dst[k] = f2bf(s[k]);
    } else {
        unsigned short* dst = &Wo_[(size_t)n*KS];
        for (int k = threadIdx.x; k < H; k += 256){
            float v = s[k];
            unsigned short hi = f2bf(v);
            dst[k]     = hi;
            dst[H + k] = f2bf(v - bf2f(hi));
        }
    }
}

// ---------------------------------------------------------------------------
// GEMM, r2-proven structure. 128x128 tile, 4 waves, BK=32.
// MODE 1 (QKV): 1-term bf16, K=768, lda/ldb=768; epilogue scatters
//   Qh (x0.125) / Kh to [b][h][s][d], Vh to V^T [b][h][d][s]  (hi only).
// MODE 0 (out-proj): 3-term split, K'=2304, lda/ldb=1536, fp32 store + bias.
// ---------------------------------------------------------------------------
template<int MODE>
__global__ __launch_bounds__(256) void gemm_split(
    const unsigned short* __restrict__ A, const unsigned short* __restrict__ Bm,
    const float* __restrict__ b0, const float* __restrict__ b1,
    const float* __restrict__ b2,
    float* __restrict__ out,
    unsigned short* __restrict__ Qh, unsigned short* __restrict__ Kh,
    unsigned short* __restrict__ Vh)
{
    constexpr int LDA  = (MODE==1) ? H : KS;
    constexpr int KEND = (MODE==1) ? H : KP;

    __shared__ unsigned short As[128*32];
    __shared__ unsigned short Bs[128*32];
    const int tid = threadIdx.x, lane = tid & 63, wave = tid >> 6;
    const int m0 = blockIdx.x*128, n0 = blockIdx.y*128;
    const int wr = wave >> 1, wc = wave & 1;
    const int frow = lane & 15, foct = lane >> 4;
    const int arow = lane >> 2;
    const int achk = ((lane & 3) ^ (arow & 3)) * 8;
    const int fswz = (foct ^ (frow & 3)) * 8;

    f32x4 acc[4][4] = {};

    for (int kp = 0; kp < KEND; kp += 32){
        const int ka = (MODE==1) ? kp : ((kp < 768)  ? kp : kp - 768);
        const int kb = (MODE==1) ? kp : ((kp < 1536) ? kp : kp - 1536);
        __syncthreads();
        #pragma unroll
        for (int i = 0; i < 2; ++i){
            const int r0 = (wave*2 + i)*16;
            const int row = r0 + arow;
            GLL16(A  + (size_t)(m0+row)*LDA + ka + achk, &As[r0*32]);
            GLL16(Bm + (size_t)(n0+row)*LDA + kb + achk, &Bs[r0*32]);
        }
        __syncthreads();
        bf16x8 af[4], bfv[4];
        #pragma unroll
        for (int i = 0; i < 4; ++i)
            af[i]  = *(const bf16x8*)&As[(wr*64 + 16*i + frow)*32 + fswz];
        #pragma unroll
        for (int j = 0; j < 4; ++j)
            bfv[j] = *(const bf16x8*)&Bs[(wc*64 + 16*j + frow)*32 + fswz];
        #pragma unroll
        for (int i = 0; i < 4; ++i)
            #pragma unroll
            for (int j = 0; j < 4; ++j)
                acc[i][j] = MFMA16(af[i], bfv[j], acc[i][j]);
    }

    if (MODE == 0){
        #pragma unroll
        for (int i = 0; i < 4; ++i){
            const int m = m0 + wr*64 + 16*i + 4*foct;
            #pragma unroll
            for (int j = 0; j < 4; ++j){
                const int n = n0 + wc*64 + 16*j + frow;
                const float bb = b0[n];
                #pragma unroll
                for (int r = 0; r < 4; ++r)
                    out[(size_t)(m + r)*H + n] = acc[i][j][r] + bb;
            }
        }
    } else {
        const int sect = n0 / 768;                 // 0=Q 1=K 2=V (block-uniform)
        const float* bias = (sect==0) ? b0 : (sect==1) ? b1 : b2;
        const float qs = (sect==0) ? 0.125f : 1.0f;
        unsigned short* Ph = (sect==0) ? Qh : Kh;
        #pragma unroll
        for (int i = 0; i < 4; ++i){
            const int m  = m0 + wr*64 + 16*i + 4*foct;
            const int bb = m >> 11, ss = m & (S_-1);
            #pragma unroll
            for (int j = 0; j < 4; ++j){
                const int nn = (n0 - sect*768) + wc*64 + 16*j + frow;
                const float bv_ = bias[nn];
                const int hh = nn >> 6, dd = nn & 63;
                unsigned short hi[4];
                #pragma unroll
                for (int r = 0; r < 4; ++r)
                    hi[r] = f2bf((acc[i][j][r] + bv_) * qs);
                if (sect < 2){                     // [b][h][s][d]
                    const size_t basep = ((size_t)(bb*NH + hh)*S_)*HD + dd;
                    #pragma unroll
                    for (int r = 0; r < 4; ++r)
                        Ph[basep + (size_t)(ss + r)*HD] = hi[r];
                } else {                           // V^T [b][h][d][s]
                    const size_t a = ((size_t)(bb*NH + hh)*HD + dd)*S_ + ss;
                    ushort4 ph; ph.x=hi[0]; ph.y=hi[1]; ph.z=hi[2]; ph.w=hi[3];
                    *(ushort4*)&Vh[a] = ph;
                }
            }
        }
    }
}

// ---------------------------------------------------------------------------
// Flash attention, 32x32x16 MFMA, swapped operands, plain bf16 (1-term QK,
// 1-term PV; error-budget-verified). 2 waves x 64 q-rows; split-K=2.
// Double-buffered 32KB LDS, counted vmcnt(8) + raw s_barrier (no drains).
// Per tile per wave: 16 QK MFMA + 8 PV MFMA; V reads shared across q-blocks.
// ---------------------------------------------------------------------------
__global__ __launch_bounds__(128, 2) void attn_mfma(
    const unsigned short* __restrict__ Qh, const unsigned short* __restrict__ Kh,
    const unsigned short* __restrict__ Vh,
    const int* __restrict__ mask, float* __restrict__ Op, float* __restrict__ mlb)
{
    __shared__ unsigned short Ksh[2][64*64];
    __shared__ unsigned short Vsh[2][64*64];

    const int tid = threadIdx.x, lane = tid & 63, wave = tid >> 6;  // 2 waves
    const int q0 = blockIdx.x*128, h = blockIdx.y;
    const int b = blockIdx.z & 1, half = blockIdx.z >> 1;
    const int l31 = lane & 31, hi = lane >> 5, l7 = lane & 7;
    const size_t base  = (size_t)(b*NH + h)*S_;   // K rows [s][d]
    const size_t vbase = (size_t)(b*NH + h)*HD;   // V rows [d][s]
    const int srow = lane >> 3;                   // 8 rows per GLL (128B rows)
    const int schk = ((lane & 7) ^ srow) * 8;     // pre-swizzled source chunk
    const int NTH = (S_/64)/2;                    // 16 tiles per half
    const int t0 = half*NTH;

    // wave 0 stages K (8 GLL), wave 1 stages V^T (8 GLL)
    auto STAGE = [&](int bufi, int t){
        if (wave == 0){
            #pragma unroll
            for (int i = 0; i < 8; ++i){
                const int r0 = i*8, row = r0 + srow;
                GLL16(Kh + (base + (size_t)t*64 + row)*HD + schk, &Ksh[bufi][r0*64]);
            }
        } else {
            #pragma unroll
            for (int i = 0; i < 8; ++i){
                const int r0 = i*8, row = r0 + srow;
                GLL16(Vh + (vbase + row)*S_ + (size_t)t*64 + schk, &Vsh[bufi][r0*64]);
            }
        }
    };

    // ---- mask bits: lane L holds keys L*32..L*32+31 (batch b) ----
    unsigned mbits = 0;
    {
        const int* mp = mask + (size_t)b*S_ + lane*32;
        #pragma unroll
        for (int j = 0; j < 32; ++j) mbits |= (mp[j] ? 1u : 0u) << j;
    }

    // ---- Q fragments, two 32-col blocks (B-op: col=l31, k=hi*8+e) ----
    bf16x8 qfA[4], qfB[4];
    {
        const size_t qrA = (base + q0 + wave*64      + l31)*HD;
        const size_t qrB = (base + q0 + wave*64 + 32 + l31)*HD;
        #pragma unroll
        for (int ds = 0; ds < 4; ++ds){
            qfA[ds] = *(const bf16x8*)&Qh[qrA + ds*16 + hi*8];
            qfB[ds] = *(const bf16x8*)&Qh[qrB + ds*16 + hi*8];
        }
    }

    STAGE(0, t0);
    STAGE(1, t0 + 1);

    float mA = -1e30f, lA = 0.f, mB = -1e30f, lB = 0.f;
    f32x16 oA0 = {}, oA1 = {}, oB0 = {}, oB1 = {};

    for (int tt = 0; tt < NTH; ++tt){
        const int t = t0 + tt, cur = tt & 1;
        if (tt + 1 < NTH) asm volatile("s_waitcnt vmcnt(8)" ::: "memory");
        else              asm volatile("s_waitcnt vmcnt(0)" ::: "memory");
        asm volatile("s_barrier" ::: "memory");   // tile t visible to both waves

        // ---- S^T = K (Q/8)^T : 16 mfma, 4 indep chains ----
        f32x16 sA0 = {}, sA1 = {}, sB0 = {}, sB1 = {};
        __builtin_amdgcn_s_setprio(1);
        #pragma unroll
        for (int ds = 0; ds < 4; ++ds){
            const int c0 = ((2*ds + hi) ^ l7)*8;
            const bf16x8 kh0 = *(const bf16x8*)&Ksh[cur][l31*64 + c0];
            const bf16x8 kh1 = *(const bf16x8*)&Ksh[cur][(32+l31)*64 + c0];
            sA0 = MFMA32(kh0, qfA[ds], sA0);
            sB0 = MFMA32(kh0, qfB[ds], sB0);
            sA1 = MFMA32(kh1, qfA[ds], sA1);
            sB1 = MFMA32(kh1, qfB[ds], sB1);
        }
        __builtin_amdgcn_s_setprio(0);

        // ---- mask via preloaded bits (no memory ops) ----
        {
            const unsigned bm_lo = (unsigned)__shfl((int)mbits, 2*t);
            const unsigned bm_hi = (unsigned)__shfl((int)mbits, 2*t + 1);
            const unsigned long long mb = ((unsigned long long)bm_hi << 32) | bm_lo;
            if (~mb){
                #pragma unroll
                for (int r = 0; r < 16; ++r){
                    const int key = (r&3) + 8*(r>>2) + 4*hi;
                    if (!((mb >> key) & 1)){ sA0[r] = -1e9f; sB0[r] = -1e9f; }
                    if (!((mb >> (key+32)) & 1)){ sA1[r] = -1e9f; sB1[r] = -1e9f; }
                }
            }
        }

        bf16x8 pfA[4], pfB[4];
        // ================= q-block A: softmax + pack =================
        {
            float vmax = -1e30f;
            #pragma unroll
            for (int r = 0; r < 16; ++r) vmax = fmaxf(vmax, fmaxf(sA0[r], sA1[r]));
            vmax = fmaxf(vmax, __shfl_xor(vmax, 32));
            if (!__all(vmax <= mA + 8.f)){          // T13 defer-rescale
                const float mnew = fmaxf(mA, vmax);
                const float sc = __expf(mA - mnew);
                mA = mnew; lA *= sc;
                #pragma unroll
                for (int r = 0; r < 16; ++r){ oA0[r] *= sc; oA1[r] *= sc; }
            }
            float ps = 0.f;
            #pragma unroll
            for (int r = 0; r < 16; ++r){
                sA0[r] = __expf(sA0[r] - mA);
                sA1[r] = __expf(sA1[r] - mA);
                ps += sA0[r] + sA1[r];
            }
            ps += __shfl_xor(ps, 32);
            lA += ps;
            #pragma unroll
            for (int s = 0; s < 4; ++s){
                const f32x16& pv = (s < 2) ? sA0 : sA1;
                const int rb = (s & 1)*8;
                unsigned w0, w1, w2, w3;
                asm("v_cvt_pk_bf16_f32 %0, %1, %2" : "=v"(w0) : "v"(pv[rb+0]), "v"(pv[rb+1]));
                asm("v_cvt_pk_bf16_f32 %0, %1, %2" : "=v"(w1) : "v"(pv[rb+2]), "v"(pv[rb+3]));
                asm("v_cvt_pk_bf16_f32 %0, %1, %2" : "=v"(w2) : "v"(pv[rb+4]), "v"(pv[rb+5]));
                asm("v_cvt_pk_bf16_f32 %0, %1, %2" : "=v"(w3) : "v"(pv[rb+6]), "v"(pv[rb+7]));
                const unsigned u0 = (unsigned)__shfl_xor((int)w0, 32);
                const unsigned u1 = (unsigned)__shfl_xor((int)w1, 32);
                const unsigned u2 = (unsigned)__shfl_xor((int)w2, 32);
                const unsigned u3 = (unsigned)__shfl_xor((int)w3, 32);
                union { uint4 u; bf16x8 v; } pk;
                pk.u.x = hi ? u2 : w0;
                pk.u.y = hi ? u3 : w1;
                pk.u.z = hi ? w2 : u0;
                pk.u.w = hi ? w3 : u1;
                pfA[s] = pk.v;
            }
        }
        // ================= q-block B: softmax + pack =================
        {
            float vmax = -1e30f;
            #pragma unroll
            for (int r = 0; r < 16; ++r) vmax = fmaxf(vmax, fmaxf(sB0[r], sB1[r]));
            vmax = fmaxf(vmax, __shfl_xor(vmax, 32));
            if (!__all(vmax <= mB + 8.f)){
                const float mnew = fmaxf(mB, vmax);
                const float sc = __expf(mB - mnew);
                mB = mnew; lB *= sc;
                #pragma unroll
                for (int r = 0; r < 16; ++r){ oB0[r] *= sc; oB1[r] *= sc; }
            }
            float ps = 0.f;
            #pragma unroll
            for (int r = 0; r < 16; ++r){
                sB0[r] = __expf(sB0[r] - mB);
                sB1[r] = __expf(sB1[r] - mB);
                ps += sB0[r] + sB1[r];
            }
            ps += __shfl_xor(ps, 32);
            lB += ps;
            #pragma unroll
            for (int s = 0; s < 4; ++s){
                const f32x16& pv = (s < 2) ? sB0 : sB1;
                const int rb = (s & 1)*8;
                unsigned w0, w1, w2, w3;
                asm("v_cvt_pk_bf16_f32 %0, %1, %2" : "=v"(w0) : "v"(pv[rb+0]), "v"(pv[rb+1]));
                asm("v_cvt_pk_bf16_f32 %0, %1, %2" : "=v"(w1) : "v"(pv[rb+2]), "v"(pv[rb+3]));
                asm("v_cvt_pk_bf16_f32 %0, %1, %2" : "=v"(w2) : "v"(pv[rb+4]), "v"(pv[rb+5]));
                asm("v_cvt_pk_bf16_f32 %0, %1, %2" : "=v"(w3) : "v"(pv[rb+6]), "v"(pv[rb+7]));
                const unsigned u0 = (unsigned)__shfl_xor((int)w0, 32);
                const unsigned u1 = (unsigned)__shfl_xor((int)w1, 32);
                const unsigned u2 = (unsigned)__shfl_xor((int)w2, 32);
                const unsigned u3 = (unsigned)__shfl_xor((int)w3, 32);
                union { uint4 u; bf16x8 v; } pk;
                pk.u.x = hi ? u2 : w0;
                pk.u.y = hi ? u3 : w1;
                pk.u.z = hi ? w2 : u0;
                pk.u.w = hi ? w3 : u1;
                pfB[s] = pk.v;
            }
        }

        // ---- O^T += V^T P^T : 8 mfma, V reads shared across A/B ----
        __builtin_amdgcn_s_setprio(1);
        #pragma unroll
        for (int s = 0; s < 4; ++s){
            const int c0 = ((2*s + hi) ^ l7)*8;
            const bf16x8 vh0 = *(const bf16x8*)&Vsh[cur][l31*64 + c0];
            const bf16x8 vh1 = *(const bf16x8*)&Vsh[cur][(32+l31)*64 + c0];
            oA0 = MFMA32(vh0, pfA[s], oA0);
            oB0 = MFMA32(vh0, pfB[s], oB0);
            oA1 = MFMA32(vh1, pfA[s], oA1);
            oB1 = MFMA32(vh1, pfB[s], oB1);
        }
        __builtin_amdgcn_s_setprio(0);

        asm volatile("s_barrier" ::: "memory");   // both waves done with buf[cur]
        if (tt + 2 < NTH) STAGE(cur, t + 2);      // overwrite freed buffer
    }

    // ---- epilogue: store UNNORMALIZED partial O (fp32) + (m,l) ----
    #pragma unroll
    for (int qb = 0; qb < 2; ++qb){
        const int qg = q0 + wave*64 + qb*32 + l31;
        const f32x16& ov0 = qb ? oB0 : oA0;
        const f32x16& ov1 = qb ? oB1 : oA1;
        float* Od = Op + ((((size_t)half*B_ + b)*NH + h)*S_ + qg)*HD;
        #pragma unroll
        for (int a = 0; a < 4; ++a){
            const int d0 = 8*a + 4*hi;
            f32x4 v0, v1;
            #pragma unroll
            for (int r = 0; r < 4; ++r){ v0[r] = ov0[a*4+r]; v1[r] = ov1[a*4+r]; }
            *(f32x4*)&Od[d0]      = v0;
            *(f32x4*)&Od[32 + d0] = v1;
        }
        if (hi == 0){
            const size_t mi = (((size_t)half*B_ + b)*NH + h)*S_ + qg;
            mlb[mi*2]     = qb ? mB : mA;
            mlb[mi*2 + 1] = qb ? lB : lA;
        }
    }
}

// ---------------------------------------------------------------------------
// Merge the two k-halves: O = (O0 w0 + O1 w1) / (l0 w0 + l1 w1), w_i=e^{m_i-m}
// Writes Cs in split-bf16 form for the 3-term out-proj.
// ---------------------------------------------------------------------------
__global__ __launch_bounds__(256) void attn_combine(
    const float* __restrict__ Op, const float* __restrict__ mlb,
    unsigned short* __restrict__ Cs)
{
    const int tid = threadIdx.x;
    const int gq = blockIdx.x*16 + (tid >> 4);       // over B*NH*S
    const int dl = (tid & 15)*4;
    const int s = gq & (S_-1);
    const int bh = gq >> 11;
    const int h = bh % NH, b = bh / NH;
    const size_t NQ = (size_t)B_*NH*S_;

    const float m0 = mlb[(size_t)gq*2],      l0 = mlb[(size_t)gq*2 + 1];
    const float m1 = mlb[(NQ + gq)*2],       l1 = mlb[(NQ + gq)*2 + 1];
    const float mm = fmaxf(m0, m1);
    const float w0 = __expf(m0 - mm), w1 = __expf(m1 - mm);
    const float inv = 1.0f / (l0*w0 + l1*w1);

    const float4 O0 = *(const float4*)&Op[(size_t)gq*HD + dl];
    const float4 O1 = *(const float4*)&Op[(NQ + gq)*HD + dl];
    float v0 = (O0.x*w0 + O1.x*w1)*inv;
    float v1 = (O0.y*w0 + O1.y*w1)*inv;
    float v2 = (O0.z*w0 + O1.z*w1)*inv;
    float v3 = (O0.w*w0 + O1.w*w1)*inv;

    const size_t g = ((size_t)b*S_ + s)*KS + h*HD + dl;
    ushort4 ph, pl;
    ph.x = f2bf(v0); pl.x = f2bf(v0 - bf2f(ph.x));
    ph.y = f2bf(v1); pl.y = f2bf(v1 - bf2f(ph.y));
    ph.z = f2bf(v2); pl.z = f2bf(v2 - bf2f(ph.z));
    ph.w = f2bf(v3); pl.w = f2bf(v3 - bf2f(ph.w));
    *(ushort4*)&Cs[g]       = ph;
    *(ushort4*)&Cs[g + 768] = pl;
}

extern "C" void kernel_launch(void* const* d_in, const int* in_sizes, int n_in,
                              void* d_out, int out_size, void* d_ws, size_t ws_size,
                              hipStream_t stream) {
    const float* hs = (const float*)d_in[0];
    const int*  msk = (const int*)  d_in[1];
    const float* wq = (const float*)d_in[2];
    const float* bq = (const float*)d_in[3];
    const float* wk = (const float*)d_in[4];
    const float* bk = (const float*)d_in[5];
    const float* wv = (const float*)d_in[6];
    const float* bv = (const float*)d_in[7];
    const float* wo = (const float*)d_in[8];
    const float* bo = (const float*)d_in[9];
    float* out = (float*)d_out;

    const size_t XH_E   = (size_t)MTOT*H;        // 3.1M shorts
    const size_t WQKV_E = (size_t)2304*H;
    const size_t WO_E   = (size_t)768*KS;
    const size_t QKV_E  = (size_t)B_*NH*S_*HD;   // 3.1M shorts
    const size_t CS_E   = (size_t)MTOT*KS;       // 6.3M shorts

    unsigned short* p = (unsigned short*)d_ws;
    unsigned short* Xh   = p; p += XH_E;
    unsigned short* Wqkv = p; p += WQKV_E;
    unsigned short* Wo_  = p; p += WO_E;
    unsigned short* Qh = p; p += QKV_E;
    unsigned short* Kh = p; p += QKV_E;
    unsigned short* Vh = p; p += QKV_E;
    unsigned short* Cs = p; p += CS_E;
    float* Op  = (float*)p;                      // 2*QKV_E floats (25.2 MB)
    float* mlb = Op + 2*QKV_E;                   // 2*B*NH*S*2 floats (0.8 MB)

    cast_x<<<dim3(MTOT), 256, 0, stream>>>(hs, Xh);
    split_w<<<dim3(768, 4), 256, 0, stream>>>(wq, wk, wv, wo, Wqkv, Wo_);
    gemm_split<1><<<dim3(MTOT/128, 2304/128), 256, 0, stream>>>(
        Xh, Wqkv, bq, bk, bv, nullptr, Qh, Kh, Vh);
    attn_mfma<<<dim3(S_/128, NH, B_*2), 128, 0, stream>>>(
        Qh, Kh, Vh, msk, Op, mlb);
    attn_combine<<<dim3((B_*NH*S_)/16), 256, 0, stream>>>(Op, mlb, Cs);
    gemm_split<0><<<dim3(MTOT/128, H/128), 256, 0, stream>>>(
        Cs, Wo_, bo, nullptr, nullptr, out,
        nullptr, nullptr, nullptr);
}

// Round 8
// 142.203 us; speedup vs baseline: 1.6515x; 1.0748x over previous
//
#include <hip/hip_runtime.h>

#define NH   12
#define HD   64
#define H    768
#define B_   2
#define S_   2048
#define MTOT (B_*S_)   // 4096
#define KS   1536      // split storage width for ctx/Wo: [hi(768) | lo(768)]
#define KP   2304      // out-proj k' extent: hi*hi | hi*lo | lo*hi

typedef short bf16x8 __attribute__((ext_vector_type(8)));
typedef float f32x4  __attribute__((ext_vector_type(4)));
typedef float f32x16 __attribute__((ext_vector_type(16)));

#define MFMA16(a,b,c) __builtin_amdgcn_mfma_f32_16x16x32_bf16((a),(b),(c),0,0,0)
#define MFMA32(a,b,c) __builtin_amdgcn_mfma_f32_32x32x16_bf16((a),(b),(c),0,0,0)
#define GLL16(g,l) __builtin_amdgcn_global_load_lds( \
    (const __attribute__((address_space(1))) void*)(g), \
    (__attribute__((address_space(3))) void*)(l), 16, 0, 0)

__device__ __forceinline__ unsigned short f2bf(float x){
    union { float f; unsigned u; } c; c.f = x;
    unsigned r = (c.u + 0x7FFFu + ((c.u >> 16) & 1u)) >> 16;   // RNE
    return (unsigned short)r;
}
__device__ __forceinline__ float bf2f(unsigned short b){
    union { unsigned u; float f; } c; c.u = ((unsigned)b) << 16;
    return c.f;
}

// ---------------------------------------------------------------------------
// Pre-passes. X: hi-only cast (feeds 1-term QKV GEMM).
// W: Wq/Wk/Wv hi-only; Wo split [hi|lo] (out-proj stays 3-term).
// ---------------------------------------------------------------------------
__global__ __launch_bounds__(256) void cast_x(
    const float* __restrict__ src, unsigned short* __restrict__ dst)
{
    const int m = blockIdx.x;
    const float* s = src + (size_t)m * H;
    unsigned short* d = dst + (size_t)m * H;
    for (int k = threadIdx.x; k < H; k += 256) d[k] = f2bf(s[k]);
}

__global__ __launch_bounds__(256) void split_w(
    const float* __restrict__ wq, const float* __restrict__ wk,
    const float* __restrict__ wv, const float* __restrict__ wo,
    unsigned short* __restrict__ Wqkv, unsigned short* __restrict__ Wo_)
{
    const int n = blockIdx.x;      // 0..767
    const int w = blockIdx.y;      // 0..3
    const float* src = (w==0)?wq:(w==1)?wk:(w==2)?wv:wo;
    const float* s = src + (size_t)n * H;
    if (w < 3){
        unsigned short* dst = &Wqkv[(size_t)(w*768 + n)*H];
        for (int k = threadIdx.x; k < H; k += 256) dst[k] = f2bf(s[k]);
    } else {
        unsigned short* dst = &Wo_[(size_t)n*KS];
        for (int k = threadIdx.x; k < H; k += 256){
            float v = s[k];
            unsigned short hi = f2bf(v);
            dst[k]     = hi;
            dst[H + k] = f2bf(v - bf2f(hi));
        }
    }
}

// ---------------------------------------------------------------------------
// GEMM, r2-proven structure. 128x128 tile, 4 waves, BK=32.
// MODE 1 (QKV): 1-term bf16, K=768; epilogue scatters Qh(x0.125)/Kh to
//   [b][h][s][d], Vh to V^T [b][h][d][s].
// MODE 0 (out-proj): 3-term split, K'=2304, lda/ldb=1536, fp32 store + bias.
// ---------------------------------------------------------------------------
template<int MODE>
__global__ __launch_bounds__(256) void gemm_split(
    const unsigned short* __restrict__ A, const unsigned short* __restrict__ Bm,
    const float* __restrict__ b0, const float* __restrict__ b1,
    const float* __restrict__ b2,
    float* __restrict__ out,
    unsigned short* __restrict__ Qh, unsigned short* __restrict__ Kh,
    unsigned short* __restrict__ Vh)
{
    constexpr int LDA  = (MODE==1) ? H : KS;
    constexpr int KEND = (MODE==1) ? H : KP;

    __shared__ unsigned short As[128*32];
    __shared__ unsigned short Bs[128*32];
    const int tid = threadIdx.x, lane = tid & 63, wave = tid >> 6;
    const int m0 = blockIdx.x*128, n0 = blockIdx.y*128;
    const int wr = wave >> 1, wc = wave & 1;
    const int frow = lane & 15, foct = lane >> 4;
    const int arow = lane >> 2;
    const int achk = ((lane & 3) ^ (arow & 3)) * 8;
    const int fswz = (foct ^ (frow & 3)) * 8;

    f32x4 acc[4][4] = {};

    for (int kp = 0; kp < KEND; kp += 32){
        const int ka = (MODE==1) ? kp : ((kp < 768)  ? kp : kp - 768);
        const int kb = (MODE==1) ? kp : ((kp < 1536) ? kp : kp - 1536);
        __syncthreads();
        #pragma unroll
        for (int i = 0; i < 2; ++i){
            const int r0 = (wave*2 + i)*16;
            const int row = r0 + arow;
            GLL16(A  + (size_t)(m0+row)*LDA + ka + achk, &As[r0*32]);
            GLL16(Bm + (size_t)(n0+row)*LDA + kb + achk, &Bs[r0*32]);
        }
        __syncthreads();
        bf16x8 af[4], bfv[4];
        #pragma unroll
        for (int i = 0; i < 4; ++i)
            af[i]  = *(const bf16x8*)&As[(wr*64 + 16*i + frow)*32 + fswz];
        #pragma unroll
        for (int j = 0; j < 4; ++j)
            bfv[j] = *(const bf16x8*)&Bs[(wc*64 + 16*j + frow)*32 + fswz];
        #pragma unroll
        for (int i = 0; i < 4; ++i)
            #pragma unroll
            for (int j = 0; j < 4; ++j)
                acc[i][j] = MFMA16(af[i], bfv[j], acc[i][j]);
    }

    if (MODE == 0){
        #pragma unroll
        for (int i = 0; i < 4; ++i){
            const int m = m0 + wr*64 + 16*i + 4*foct;
            #pragma unroll
            for (int j = 0; j < 4; ++j){
                const int n = n0 + wc*64 + 16*j + frow;
                const float bb = b0[n];
                #pragma unroll
                for (int r = 0; r < 4; ++r)
                    out[(size_t)(m + r)*H + n] = acc[i][j][r] + bb;
            }
        }
    } else {
        const int sect = n0 / 768;                 // 0=Q 1=K 2=V (block-uniform)
        const float* bias = (sect==0) ? b0 : (sect==1) ? b1 : b2;
        const float qs = (sect==0) ? 0.125f : 1.0f;
        unsigned short* Ph = (sect==0) ? Qh : Kh;
        #pragma unroll
        for (int i = 0; i < 4; ++i){
            const int m  = m0 + wr*64 + 16*i + 4*foct;
            const int bb = m >> 11, ss = m & (S_-1);
            #pragma unroll
            for (int j = 0; j < 4; ++j){
                const int nn = (n0 - sect*768) + wc*64 + 16*j + frow;
                const float bv_ = bias[nn];
                const int hh = nn >> 6, dd = nn & 63;
                unsigned short hi[4];
                #pragma unroll
                for (int r = 0; r < 4; ++r)
                    hi[r] = f2bf((acc[i][j][r] + bv_) * qs);
                if (sect < 2){                     // [b][h][s][d]
                    const size_t basep = ((size_t)(bb*NH + hh)*S_)*HD + dd;
                    #pragma unroll
                    for (int r = 0; r < 4; ++r)
                        Ph[basep + (size_t)(ss + r)*HD] = hi[r];
                } else {                           // V^T [b][h][d][s]
                    const size_t a = ((size_t)(bb*NH + hh)*HD + dd)*S_ + ss;
                    ushort4 ph; ph.x=hi[0]; ph.y=hi[1]; ph.z=hi[2]; ph.w=hi[3];
                    *(ushort4*)&Vh[a] = ph;
                }
            }
        }
    }
}

// ---------------------------------------------------------------------------
// Flash attention, 32x32x16 MFMA, swapped operands, plain bf16.
// 4 waves x 32 q-rows (was 2x64): same grid/LDS but 12 waves/CU resident
// (r7 was grid-limited at 6). Split-K=2; 32KB dbuf; counted vmcnt(4) + raw
// s_barrier; staging split 4 ways (w0,w1 -> K; w2,w3 -> V^T).
// Per tile per wave: 8 QK MFMA + 8 PV MFMA + 32 exps.
// ---------------------------------------------------------------------------
__global__ __launch_bounds__(256, 3) void attn_mfma(
    const unsigned short* __restrict__ Qh, const unsigned short* __restrict__ Kh,
    const unsigned short* __restrict__ Vh,
    const int* __restrict__ mask, float* __restrict__ Op, float* __restrict__ mlb)
{
    __shared__ unsigned short Ksh[2][64*64];
    __shared__ unsigned short Vsh[2][64*64];

    const int tid = threadIdx.x, lane = tid & 63, wave = tid >> 6;  // 4 waves
    const int q0 = blockIdx.x*128, h = blockIdx.y;
    const int b = blockIdx.z & 1, half = blockIdx.z >> 1;
    const int l31 = lane & 31, hi = lane >> 5, l7 = lane & 7;
    const size_t base  = (size_t)(b*NH + h)*S_;   // K rows [s][d]
    const size_t vbase = (size_t)(b*NH + h)*HD;   // V rows [d][s]
    const int srow = lane >> 3;                   // 8 rows per GLL (128B rows)
    const int schk = ((lane & 7) ^ srow) * 8;     // pre-swizzled source chunk
    const int NTH = (S_/64)/2;                    // 16 tiles per half
    const int t0 = half*NTH;

    // 16 GLL per tile, 4 per wave: w0/w1 stage K rows 0..31/32..63; w2/w3 V.
    auto STAGE = [&](int bufi, int t){
        if (wave < 2){
            #pragma unroll
            for (int i = 0; i < 4; ++i){
                const int r0 = (wave*4 + i)*8, row = r0 + srow;
                GLL16(Kh + (base + (size_t)t*64 + row)*HD + schk, &Ksh[bufi][r0*64]);
            }
        } else {
            #pragma unroll
            for (int i = 0; i < 4; ++i){
                const int r0 = ((wave-2)*4 + i)*8, row = r0 + srow;
                GLL16(Vh + (vbase + row)*S_ + (size_t)t*64 + schk, &Vsh[bufi][r0*64]);
            }
        }
    };

    // ---- mask bits: lane L holds keys L*32..L*32+31 (batch b) ----
    unsigned mbits = 0;
    {
        const int* mp = mask + (size_t)b*S_ + lane*32;
        #pragma unroll
        for (int j = 0; j < 32; ++j) mbits |= (mp[j] ? 1u : 0u) << j;
    }

    // ---- Q fragments, one 32-col block per wave (B-op: col=l31, k=hi*8+e) ----
    bf16x8 qf[4];
    {
        const size_t qr = (base + q0 + wave*32 + l31)*HD;
        #pragma unroll
        for (int ds = 0; ds < 4; ++ds)
            qf[ds] = *(const bf16x8*)&Qh[qr + ds*16 + hi*8];
    }

    STAGE(0, t0);
    STAGE(1, t0 + 1);

    float mR = -1e30f, lR = 0.f;
    f32x16 o0 = {}, o1 = {};

    for (int tt = 0; tt < NTH; ++tt){
        const int t = t0 + tt, cur = tt & 1;
        if (tt + 1 < NTH) asm volatile("s_waitcnt vmcnt(4)" ::: "memory");
        else              asm volatile("s_waitcnt vmcnt(0)" ::: "memory");
        asm volatile("s_barrier" ::: "memory");   // tile t visible to all waves

        // ---- S^T = K (Q/8)^T : 8 mfma, 2 indep chains ----
        f32x16 s0 = {}, s1 = {};
        __builtin_amdgcn_s_setprio(1);
        #pragma unroll
        for (int ds = 0; ds < 4; ++ds){
            const int c0 = ((2*ds + hi) ^ l7)*8;
            const bf16x8 kh0 = *(const bf16x8*)&Ksh[cur][l31*64 + c0];
            const bf16x8 kh1 = *(const bf16x8*)&Ksh[cur][(32+l31)*64 + c0];
            s0 = MFMA32(kh0, qf[ds], s0);
            s1 = MFMA32(kh1, qf[ds], s1);
        }
        __builtin_amdgcn_s_setprio(0);

        // ---- mask via preloaded bits (no memory ops) ----
        {
            const unsigned bm_lo = (unsigned)__shfl((int)mbits, 2*t);
            const unsigned bm_hi = (unsigned)__shfl((int)mbits, 2*t + 1);
            const unsigned long long mb = ((unsigned long long)bm_hi << 32) | bm_lo;
            if (~mb){
                #pragma unroll
                for (int r = 0; r < 16; ++r){
                    const int key = (r&3) + 8*(r>>2) + 4*hi;
                    if (!((mb >> key) & 1))      s0[r] = -1e9f;
                    if (!((mb >> (key+32)) & 1)) s1[r] = -1e9f;
                }
            }
        }

        // ---- online softmax (lane-local + 1 cross-half shfl) ----
        float vmax = -1e30f;
        #pragma unroll
        for (int r = 0; r < 16; ++r) vmax = fmaxf(vmax, fmaxf(s0[r], s1[r]));
        vmax = fmaxf(vmax, __shfl_xor(vmax, 32));
        if (!__all(vmax <= mR + 8.f)){            // T13 defer-rescale
            const float mnew = fmaxf(mR, vmax);
            const float sc = __expf(mR - mnew);
            mR = mnew; lR *= sc;
            #pragma unroll
            for (int r = 0; r < 16; ++r){ o0[r] *= sc; o1[r] *= sc; }
        }
        float ps = 0.f;
        #pragma unroll
        for (int r = 0; r < 16; ++r){
            s0[r] = __expf(s0[r] - mR);
            s1[r] = __expf(s1[r] - mR);
            ps += s0[r] + s1[r];
        }
        ps += __shfl_xor(ps, 32);
        lR += ps;

        // ---- pack P^T to bf16 B-frags in-register (cvt_pk + swap) ----
        bf16x8 pf[4];
        #pragma unroll
        for (int s = 0; s < 4; ++s){
            const f32x16& pv = (s < 2) ? s0 : s1;
            const int rb = (s & 1)*8;
            unsigned w0, w1, w2, w3;
            asm("v_cvt_pk_bf16_f32 %0, %1, %2" : "=v"(w0) : "v"(pv[rb+0]), "v"(pv[rb+1]));
            asm("v_cvt_pk_bf16_f32 %0, %1, %2" : "=v"(w1) : "v"(pv[rb+2]), "v"(pv[rb+3]));
            asm("v_cvt_pk_bf16_f32 %0, %1, %2" : "=v"(w2) : "v"(pv[rb+4]), "v"(pv[rb+5]));
            asm("v_cvt_pk_bf16_f32 %0, %1, %2" : "=v"(w3) : "v"(pv[rb+6]), "v"(pv[rb+7]));
            const unsigned u0 = (unsigned)__shfl_xor((int)w0, 32);
            const unsigned u1 = (unsigned)__shfl_xor((int)w1, 32);
            const unsigned u2 = (unsigned)__shfl_xor((int)w2, 32);
            const unsigned u3 = (unsigned)__shfl_xor((int)w3, 32);
            union { uint4 u; bf16x8 v; } pk;
            pk.u.x = hi ? u2 : w0;
            pk.u.y = hi ? u3 : w1;
            pk.u.z = hi ? w2 : u0;
            pk.u.w = hi ? w3 : u1;
            pf[s] = pk.v;
        }

        // ---- O^T += V^T P^T : 8 mfma, 2 indep chains ----
        __builtin_amdgcn_s_setprio(1);
        #pragma unroll
        for (int s = 0; s < 4; ++s){
            const int c0 = ((2*s + hi) ^ l7)*8;
            const bf16x8 vh0 = *(const bf16x8*)&Vsh[cur][l31*64 + c0];
            const bf16x8 vh1 = *(const bf16x8*)&Vsh[cur][(32+l31)*64 + c0];
            o0 = MFMA32(vh0, pf[s], o0);
            o1 = MFMA32(vh1, pf[s], o1);
        }
        __builtin_amdgcn_s_setprio(0);

        asm volatile("s_barrier" ::: "memory");   // all waves done with buf[cur]
        if (tt + 2 < NTH) STAGE(cur, t + 2);      // overwrite freed buffer
    }

    // ---- epilogue: store UNNORMALIZED partial O (fp32) + (m,l) ----
    const int qg = q0 + wave*32 + l31;
    float* Od = Op + ((((size_t)half*B_ + b)*NH + h)*S_ + qg)*HD;
    #pragma unroll
    for (int a = 0; a < 4; ++a){
        const int d0 = 8*a + 4*hi;
        f32x4 v0, v1;
        #pragma unroll
        for (int r = 0; r < 4; ++r){ v0[r] = o0[a*4+r]; v1[r] = o1[a*4+r]; }
        *(f32x4*)&Od[d0]      = v0;
        *(f32x4*)&Od[32 + d0] = v1;
    }
    if (hi == 0){
        const size_t mi = (((size_t)half*B_ + b)*NH + h)*S_ + qg;
        mlb[mi*2]     = mR;
        mlb[mi*2 + 1] = lR;
    }
}

// ---------------------------------------------------------------------------
// Merge the two k-halves: O = (O0 w0 + O1 w1) / (l0 w0 + l1 w1), w_i=e^{m_i-m}
// Writes Cs in split-bf16 form for the 3-term out-proj.
// ---------------------------------------------------------------------------
__global__ __launch_bounds__(256) void attn_combine(
    const float* __restrict__ Op, const float* __restrict__ mlb,
    unsigned short* __restrict__ Cs)
{
    const int tid = threadIdx.x;
    const int gq = blockIdx.x*16 + (tid >> 4);       // over B*NH*S
    const int dl = (tid & 15)*4;
    const int s = gq & (S_-1);
    const int bh = gq >> 11;
    const int h = bh % NH, b = bh / NH;
    const size_t NQ = (size_t)B_*NH*S_;

    const float m0 = mlb[(size_t)gq*2],      l0 = mlb[(size_t)gq*2 + 1];
    const float m1 = mlb[(NQ + gq)*2],       l1 = mlb[(NQ + gq)*2 + 1];
    const float mm = fmaxf(m0, m1);
    const float w0 = __expf(m0 - mm), w1 = __expf(m1 - mm);
    const float inv = 1.0f / (l0*w0 + l1*w1);

    const float4 O0 = *(const float4*)&Op[(size_t)gq*HD + dl];
    const float4 O1 = *(const float4*)&Op[(NQ + gq)*HD + dl];
    float v0 = (O0.x*w0 + O1.x*w1)*inv;
    float v1 = (O0.y*w0 + O1.y*w1)*inv;
    float v2 = (O0.z*w0 + O1.z*w1)*inv;
    float v3 = (O0.w*w0 + O1.w*w1)*inv;

    const size_t g = ((size_t)b*S_ + s)*KS + h*HD + dl;
    ushort4 ph, pl;
    ph.x = f2bf(v0); pl.x = f2bf(v0 - bf2f(ph.x));
    ph.y = f2bf(v1); pl.y = f2bf(v1 - bf2f(ph.y));
    ph.z = f2bf(v2); pl.z = f2bf(v2 - bf2f(ph.z));
    ph.w = f2bf(v3); pl.w = f2bf(v3 - bf2f(ph.w));
    *(ushort4*)&Cs[g]       = ph;
    *(ushort4*)&Cs[g + 768] = pl;
}

extern "C" void kernel_launch(void* const* d_in, const int* in_sizes, int n_in,
                              void* d_out, int out_size, void* d_ws, size_t ws_size,
                              hipStream_t stream) {
    const float* hs = (const float*)d_in[0];
    const int*  msk = (const int*)  d_in[1];
    const float* wq = (const float*)d_in[2];
    const float* bq = (const float*)d_in[3];
    const float* wk = (const float*)d_in[4];
    const float* bk = (const float*)d_in[5];
    const float* wv = (const float*)d_in[6];
    const float* bv = (const float*)d_in[7];
    const float* wo = (const float*)d_in[8];
    const float* bo = (const float*)d_in[9];
    float* out = (float*)d_out;

    const size_t XH_E   = (size_t)MTOT*H;        // 3.1M shorts
    const size_t WQKV_E = (size_t)2304*H;
    const size_t WO_E   = (size_t)768*KS;
    const size_t QKV_E  = (size_t)B_*NH*S_*HD;   // 3.1M shorts
    const size_t CS_E   = (size_t)MTOT*KS;       // 6.3M shorts

    unsigned short* p = (unsigned short*)d_ws;
    unsigned short* Xh   = p; p += XH_E;
    unsigned short* Wqkv = p; p += WQKV_E;
    unsigned short* Wo_  = p; p += WO_E;
    unsigned short* Qh = p; p += QKV_E;
    unsigned short* Kh = p; p += QKV_E;
    unsigned short* Vh = p; p += QKV_E;
    unsigned short* Cs = p; p += CS_E;
    float* Op  = (float*)p;                      // 2*QKV_E floats (25.2 MB)
    float* mlb = Op + 2*QKV_E;                   // 2*B*NH*S*2 floats (0.8 MB)

    cast_x<<<dim3(MTOT), 256, 0, stream>>>(hs, Xh);
    split_w<<<dim3(768, 4), 256, 0, stream>>>(wq, wk, wv, wo, Wqkv, Wo_);
    gemm_split<1><<<dim3(MTOT/128, 2304/128), 256, 0, stream>>>(
        Xh, Wqkv, bq, bk, bv, nullptr, Qh, Kh, Vh);
    attn_mfma<<<dim3(S_/128, NH, B_*2), 256, 0, stream>>>(
        Qh, Kh, Vh, msk, Op, mlb);
    attn_combine<<<dim3((B_*NH*S_)/16), 256, 0, stream>>>(Op, mlb, Cs);
    gemm_split<0><<<dim3(MTOT/128, H/128), 256, 0, stream>>>(
        Cs, Wo_, bo, nullptr, nullptr, out,
        nullptr, nullptr, nullptr);
}